// Round 1
// baseline (35.885 us; speedup 1.0000x reference)
//
#include <hip/hip_runtime.h>
#include <float.h>

// Problem constants (fixed by the reference setup_inputs()).
#define N_BATCH 4
#define P1 8192
#define P2 8192
#define D 3

#define CHUNK 256                  // targets staged in LDS per block
#define NCHUNK (P2 / CHUNK)        // 32
#define RSRC 8                     // source points per thread
#define TPB 256
#define SRC_PER_BLK (TPB * RSRC)   // 2048
#define NSRCBLK (P1 / SRC_PER_BLK) // 4
#define NMIN (N_BATCH * P1)        // 32768 per-source mins in workspace

__global__ void chamfer_init_mins(unsigned* __restrict__ mins) {
    int i = blockIdx.x * blockDim.x + threadIdx.x;
    if (i < NMIN) mins[i] = 0x7F7FFFFFu;  // bit pattern of FLT_MAX
}

__global__ __launch_bounds__(TPB) void chamfer_main(
        const float* __restrict__ src,
        const float* __restrict__ tgt,
        unsigned* __restrict__ mins) {
    const int bid = blockIdx.x;
    const int c   = bid % NCHUNK;
    const int sb  = (bid / NCHUNK) % NSRCBLK;
    const int n   = bid / (NCHUNK * NSRCBLK);
    const int t   = threadIdx.x;

    __shared__ float4 sT[CHUNK];   // (-2*y0, -2*y1, -2*y2, y.y) per target

    // Stage one 256-target chunk into LDS (coalesced 3 KB read).
    {
        const int j = c * CHUNK + t;
        const float* p = tgt + ((size_t)n * P2 + j) * D;
        const float y0 = p[0], y1 = p[1], y2 = p[2];
        sT[t] = make_float4(-2.0f * y0, -2.0f * y1, -2.0f * y2,
                            y0 * y0 + y1 * y1 + y2 * y2);
    }
    __syncthreads();

    // Each thread owns RSRC source points, interleaved for coalescing.
    float x0[RSRC], x1[RSRC], x2[RSRC], xsq[RSRC], m[RSRC];
#pragma unroll
    for (int i = 0; i < RSRC; ++i) {
        const int s = sb * SRC_PER_BLK + i * TPB + t;
        const float* p = src + ((size_t)n * P1 + s) * D;
        x0[i] = p[0]; x1[i] = p[1]; x2[i] = p[2];
        xsq[i] = x0[i] * x0[i] + x1[i] * x1[i] + x2[i] * x2[i];
        m[i] = FLT_MAX;
    }

    // Inner loop: 1 broadcast ds_read_b128 per target, then 8x(3 FMA + 1 min).
#pragma unroll 4
    for (int j = 0; j < CHUNK; ++j) {
        const float4 y = sT[j];
#pragma unroll
        for (int i = 0; i < RSRC; ++i) {
            float d = __builtin_fmaf(x0[i], y.x, y.w);
            d = __builtin_fmaf(x1[i], y.y, d);
            d = __builtin_fmaf(x2[i], y.z, d);
            m[i] = fminf(m[i], d);
        }
    }

    // Per-chunk clamped min; clamp commutes with min, so atomicMin on the
    // uint bit pattern (valid total order for non-negative floats) is exact.
#pragma unroll
    for (int i = 0; i < RSRC; ++i) {
        const int s = sb * SRC_PER_BLK + i * TPB + t;
        const float v = fmaxf(xsq[i] + m[i], 0.0f);
        atomicMin(&mins[n * P1 + s], __float_as_uint(v));
    }
}

__global__ void chamfer_reduce(const float* __restrict__ mins,
                               float* __restrict__ out) {
    const int tid = blockIdx.x * blockDim.x + threadIdx.x;
    float v = 0.0f;
    for (int i = tid; i < NMIN; i += gridDim.x * blockDim.x)
        v += mins[i];
    // wave64 reduce
#pragma unroll
    for (int off = 32; off > 0; off >>= 1)
        v += __shfl_down(v, off, 64);
    __shared__ float sred[TPB / 64];
    const int lane = threadIdx.x & 63;
    const int w    = threadIdx.x >> 6;
    if (lane == 0) sred[w] = v;
    __syncthreads();
    if (threadIdx.x == 0) {
        float s = 0.0f;
#pragma unroll
        for (int i = 0; i < TPB / 64; ++i) s += sred[i];
        atomicAdd(out, s * (1.0f / N_BATCH));  // batch_reduction='mean'
    }
}

extern "C" void kernel_launch(void* const* d_in, const int* in_sizes, int n_in,
                              void* d_out, int out_size, void* d_ws, size_t ws_size,
                              hipStream_t stream) {
    const float* src = (const float*)d_in[0];  // (4, 8192, 3) f32
    const float* tgt = (const float*)d_in[1];  // (4, 8192, 3) f32
    float* out = (float*)d_out;                // scalar f32
    unsigned* mins = (unsigned*)d_ws;          // 32768 * 4B = 128 KB scratch

    // Zero the output accumulator (graph-capture-safe async memset).
    hipMemsetAsync(out, 0, sizeof(float), stream);

    chamfer_init_mins<<<(NMIN + TPB - 1) / TPB, TPB, 0, stream>>>(mins);

    const int nblocks = N_BATCH * NSRCBLK * NCHUNK;  // 4*4*32 = 512
    chamfer_main<<<nblocks, TPB, 0, stream>>>(src, tgt, mins);

    chamfer_reduce<<<64, TPB, 0, stream>>>((const float*)mins, out);
}